// Round 1
// baseline (184.965 us; speedup 1.0000x reference)
//
#include <hip/hip_runtime.h>
#include <hip/hip_bf16.h>
#include <stdint.h>

#define DM   768
#define NH   12
#define DKH  64
#define BB   2
#define SS   2048
#define MT   (BB*SS)          // 4096 rows total
#define NQKV (3*DM)           // 2304

typedef __attribute__((ext_vector_type(8))) short short8;
typedef __attribute__((ext_vector_type(4))) float f32x4;

__device__ __forceinline__ unsigned short f2bf(float f) {
    union { float f; unsigned u; } v; v.f = f;
    unsigned r = v.u + 0x7fffu + ((v.u >> 16) & 1u);
    return (unsigned short)(r >> 16);
}

// async global->LDS, 16B per lane; dst = wave-uniform base + lane*16
__device__ __forceinline__ void gload_lds16(const unsigned short* g, unsigned short* l) {
    __builtin_amdgcn_global_load_lds((const __attribute__((address_space(1))) void*)g,
                                     (__attribute__((address_space(3))) void*)l, 16, 0, 0);
}

// ---- fused input/weight conversion (one launch) ----
__launch_bounds__(256)
__global__ void k_conv(const float* __restrict__ x, unsigned short* __restrict__ xb,
                       const float* __restrict__ wq, const float* __restrict__ wk,
                       const float* __restrict__ wv, const float* __restrict__ wo,
                       unsigned short* __restrict__ wT) {
    __shared__ float tile[32][33];
    const int t = threadIdx.x;
    if (blockIdx.x < 3072) {
        int i = blockIdx.x * 256 + t;
        const float4 v = ((const float4*)x)[i];
        ushort4 o;
        o.x = f2bf(v.x); o.y = f2bf(v.y); o.z = f2bf(v.z); o.w = f2bf(v.w);
        ((ushort4*)xb)[i] = o;
    } else {
        const int cid = blockIdx.x - 3072;            // 0..2303
        const int sel = cid / 576;
        const int rem = cid - sel * 576;
        const int kb = rem / 24, nb = rem - (rem / 24) * 24;
        const float* w = (sel == 0) ? wq : (sel == 1) ? wk : (sel == 2) ? wv : wo;
        const int k0 = kb * 32, n0 = nb * 32;
        const int tx = t & 31, ty = t >> 5;           // (32, 8)
        #pragma unroll
        for (int j = 0; j < 4; j++)
            tile[ty + 8*j][tx] = w[(size_t)(k0 + ty + 8*j) * DM + n0 + tx];
        __syncthreads();
        #pragma unroll
        for (int j = 0; j < 4; j++)
            wT[(size_t)(sel*DM + n0 + ty + 8*j) * DM + k0 + tx] = f2bf(tile[tx][ty + 8*j]);
    }
}

// ---- fused QKV projection, BK=32: Q,K [bh][s][dk] (Q pre-scaled 0.125), V^T [bh][dk][s]
__launch_bounds__(256)
__global__ void k_gemm_qkv(const unsigned short* __restrict__ xb,
                           const unsigned short* __restrict__ wT,
                           const float* __restrict__ bq, const float* __restrict__ bk,
                           const float* __restrict__ bv,
                           unsigned short* __restrict__ Qb,
                           unsigned short* __restrict__ Kb,
                           unsigned short* __restrict__ Vt) {
    __shared__ __align__(16) unsigned short As[128][32];
    __shared__ __align__(16) unsigned short Bs[128][32];
    const int t = threadIdx.x;
    const int m0 = blockIdx.x * 128;
    const int n0 = blockIdx.y * 128;
    const int wid = t >> 6, lane = t & 63, q4 = lane >> 4, l16 = lane & 15;
    const int wm = (wid >> 1) * 64, wn = (wid & 1) * 64;

    const int srow = wid * 32 + (lane >> 2);
    const int koff = (lane & 3) * 8;
    const unsigned short* AgL = xb + (size_t)(m0 + srow) * DM + koff;
    const unsigned short* AgH = AgL + (size_t)16 * DM;
    const unsigned short* BgL = wT + (size_t)(n0 + srow) * DM + koff;
    const unsigned short* BgH = BgL + (size_t)16 * DM;
    unsigned short* ldsA1 = &As[wid*32][0];
    unsigned short* ldsA2 = &As[wid*32 + 16][0];
    unsigned short* ldsB1 = &Bs[wid*32][0];
    unsigned short* ldsB2 = &Bs[wid*32 + 16][0];

    f32x4 acc[4][4];
    for (int i = 0; i < 4; i++) for (int j = 0; j < 4; j++)
        acc[i][j] = (f32x4){0.f, 0.f, 0.f, 0.f};

    for (int kt = 0; kt < DM; kt += 32) {
        gload_lds16(AgL + kt, ldsA1);
        gload_lds16(AgH + kt, ldsA2);
        gload_lds16(BgL + kt, ldsB1);
        gload_lds16(BgH + kt, ldsB2);
        __syncthreads();
        short8 af[4], bf[4];
        for (int i = 0; i < 4; i++) af[i] = *(const short8*)&As[wm + i*16 + l16][q4*8];
        for (int i = 0; i < 4; i++) bf[i] = *(const short8*)&Bs[wn + i*16 + l16][q4*8];
        for (int mi = 0; mi < 4; mi++)
            for (int ni = 0; ni < 4; ni++)
                acc[mi][ni] = __builtin_amdgcn_mfma_f32_16x16x32_bf16(af[mi], bf[ni], acc[mi][ni], 0, 0, 0);
        __syncthreads();
    }

    const int sel = n0 / DM;
    const float* bias = (sel == 0) ? bq : (sel == 1) ? bk : bv;
    for (int ni = 0; ni < 4; ni++) {
        const int col = n0 + wn + ni*16 + l16;
        const int c = col - sel * DM;
        const float bsv = bias[c];
        const int h = c >> 6, d = c & 63;
        for (int mi = 0; mi < 4; mi++) {
            for (int r = 0; r < 4; r++) {
                const int row = m0 + wm + mi*16 + q4*4 + r;
                const int b = row >> 11, s = row & 2047;
                const int bh = b * NH + h;
                float v = acc[mi][ni][r] + bsv;
                if (sel == 0) {
                    Qb[(bh*SS + s)*DKH + d] = f2bf(v * 0.125f);   // fold 1/sqrt(dk), exact
                } else if (sel == 1) {
                    Kb[(bh*SS + s)*DKH + d] = f2bf(v);
                } else {
                    Vt[(bh*DKH + d)*SS + s] = f2bf(v);            // V pre-transposed
                }
            }
        }
    }
}

// ---- causal flash attention v2: swapped-QK^T engine ----
// 384 blocks, 4 waves x 32 q-rows (128 q/block), dbuf swizzled LDS K/V (no pad),
// P stored transposed via packed 8B writes, PV = mfma(V, P) accumulating O^T.
// Block-ID pairing map: heavy singles on CUs 128..255, complementary pairs on 0..127.
__launch_bounds__(256, 3)
__global__ void k_attn(const unsigned short* __restrict__ Qb,
                       const unsigned short* __restrict__ Kb,
                       const unsigned short* __restrict__ Vt,
                       unsigned short* __restrict__ ctx) {
    __shared__ __align__(16) unsigned short Ks[2][64*64];   // [row][col^swz(row)]
    __shared__ __align__(16) unsigned short Vs[2][64*64];
    __shared__ __align__(16) unsigned short P2[4][32*64];   // per-wave P[q][key], swizzled
    const int t = threadIdx.x;
    const int wid = t >> 6, lane = t & 63, q4 = lane >> 4, l16 = lane & 15;

    // work mapping: g in heavy-first order; pair big+small on same CU slot
    const int lin = blockIdx.x;           // 0..383
    int g;
    if (lin < 128)      g = 128 + lin;    // mid blocks, paired with...
    else if (lin < 256) g = lin - 128;    // heaviest 128 as singles
    else                g = 639 - lin;    // ...lightest (lin-256 pairs lin)
    const int bh  = g % 24;
    const int qsb = 15 - g / 24;          // q super-block 0..15 (128 rows each)
    const int KT  = 2*qsb + 1;            // last 64-key tile index for this block
    const int b = bh / NH, h = bh - b * NH;
    const int qw = qsb*128 + wid*32;      // this wave's 32 q-rows
    const int ktw = (qw + 31) >> 6;       // wave's last active tile (the masked one)

    const unsigned short* Qp = Qb + (size_t)bh * SS * DKH;
    const unsigned short* Kp = Kb + (size_t)bh * SS * DKH;
    const unsigned short* Vp = Vt + (size_t)bh * DKH * SS;

    // staging: 256 threads, 2 rounds each for K and V (64 rows x 128B)
    const int sr  = t >> 3;                       // 0..31
    const int sc8 = (t & 7) * 8;                  // short col 0..56
    const int scs = sc8 ^ ((sr & 7) * 8);         // swizzled short col
    const int swz = (l16 & 7) * 8;                // fragment-read swizzle (row&7 == l16&7)

    short8 qf[2][2];
    #pragma unroll
    for (int c = 0; c < 2; c++)
        #pragma unroll
        for (int kc = 0; kc < 2; kc++)
            qf[c][kc] = *(const short8*)(Qp + (size_t)(qw + c*16 + l16)*DKH + kc*32 + q4*8);

    f32x4 accO[2][4];
    #pragma unroll
    for (int c = 0; c < 2; c++)
        #pragma unroll
        for (int j = 0; j < 4; j++) accO[c][j] = (f32x4){0.f, 0.f, 0.f, 0.f};
    float lacc[2] = {0.f, 0.f};

    {   // prologue: stage tile 0
        *(uint4*)&Ks[0][ sr      *64 + scs] = *(const uint4*)(Kp + (size_t) sr      *DKH + sc8);
        *(uint4*)&Ks[0][(sr+32)*64 + scs]   = *(const uint4*)(Kp + (size_t)(sr+32)  *DKH + sc8);
        *(uint4*)&Vs[0][ sr      *64 + scs] = *(const uint4*)(Vp + (size_t) sr      *SS  + sc8);
        *(uint4*)&Vs[0][(sr+32)*64 + scs]   = *(const uint4*)(Vp + (size_t)(sr+32)  *SS  + sc8);
    }
    __syncthreads();

    for (int kt = 0; kt <= KT; kt++) {
        const int cb = kt & 1, nb = cb ^ 1;
        const bool hasN = (kt < KT);
        uint4 nk0, nk1, nv0, nv1;
        if (hasN) {
            const int kn = (kt + 1) * 64;
            nk0 = *(const uint4*)(Kp + (size_t)(kn + sr)      * DKH + sc8);
            nk1 = *(const uint4*)(Kp + (size_t)(kn + sr + 32) * DKH + sc8);
            nv0 = *(const uint4*)(Vp + (size_t)(sr)      * SS + kn + sc8);
            nv1 = *(const uint4*)(Vp + (size_t)(sr + 32) * SS + kn + sc8);
        }
        if (kt <= ktw) {            // wave-uniform active test
            // ---- QK^T swapped: St[c][ni] = S^T, col = q (l16), row = key (q4*4+r)
            f32x4 St[2][4];
            #pragma unroll
            for (int c = 0; c < 2; c++)
                #pragma unroll
                for (int ni = 0; ni < 4; ni++) St[c][ni] = (f32x4){0.f, 0.f, 0.f, 0.f};
            __builtin_amdgcn_s_setprio(1);
            #pragma unroll
            for (int ni = 0; ni < 4; ni++) {
                const int rbase = (ni*16 + l16) * 64;
                short8 kf0 = *(const short8*)&Ks[cb][rbase + ((     q4*8) ^ swz)];
                short8 kf1 = *(const short8*)&Ks[cb][rbase + ((32 + q4*8) ^ swz)];
                St[0][ni] = __builtin_amdgcn_mfma_f32_16x16x32_bf16(kf0, qf[0][0], St[0][ni], 0, 0, 0);
                St[0][ni] = __builtin_amdgcn_mfma_f32_16x16x32_bf16(kf1, qf[0][1], St[0][ni], 0, 0, 0);
                St[1][ni] = __builtin_amdgcn_mfma_f32_16x16x32_bf16(kf0, qf[1][0], St[1][ni], 0, 0, 0);
                St[1][ni] = __builtin_amdgcn_mfma_f32_16x16x32_bf16(kf1, qf[1][1], St[1][ni], 0, 0, 0);
            }
            __builtin_amdgcn_s_setprio(0);
            // ---- softmax (no-max exp, as before) + transposed P store: 8B packed
            if (kt < ktw) {         // fully unmasked tile
                #pragma unroll
                for (int c = 0; c < 2; c++) {
                    const int prow = (c*16 + l16) * 64;
                    #pragma unroll
                    for (int ni = 0; ni < 4; ni++) {
                        float p0 = __expf(St[c][ni][0]), p1 = __expf(St[c][ni][1]);
                        float p2 = __expf(St[c][ni][2]), p3 = __expf(St[c][ni][3]);
                        lacc[c] += (p0 + p1) + (p2 + p3);
                        union { __hip_bfloat162 v; unsigned u; } u01, u23;
                        u01.v = __float22bfloat162_rn(make_float2(p0, p1));
                        u23.v = __float22bfloat162_rn(make_float2(p2, p3));
                        uint2 pk; pk.x = u01.u; pk.y = u23.u;
                        *(uint2*)&P2[wid][prow + ((ni*16 + q4*4) ^ swz)] = pk;
                    }
                }
            } else {                // the wave's single partially-masked tile
                const int kb0 = kt * 64;
                #pragma unroll
                for (int c = 0; c < 2; c++) {
                    const int qrow = qw + c*16 + l16;
                    const int prow = (c*16 + l16) * 64;
                    #pragma unroll
                    for (int ni = 0; ni < 4; ni++) {
                        const int key0 = kb0 + ni*16 + q4*4;
                        float p[4];
                        #pragma unroll
                        for (int r = 0; r < 4; r++) {
                            p[r] = (key0 + r > qrow) ? 0.f : __expf(St[c][ni][r]);
                            lacc[c] += p[r];
                        }
                        union { __hip_bfloat162 v; unsigned u; } u01, u23;
                        u01.v = __float22bfloat162_rn(make_float2(p[0], p[1]));
                        u23.v = __float22bfloat162_rn(make_float2(p[2], p[3]));
                        uint2 pk; pk.x = u01.u; pk.y = u23.u;
                        *(uint2*)&P2[wid][prow + ((ni*16 + q4*4) ^ swz)] = pk;
                    }
                }
            }
            asm volatile("s_waitcnt lgkmcnt(0)" ::: "memory");   // wave-private P round-trip
            short8 pf[2][2];
            #pragma unroll
            for (int c = 0; c < 2; c++)
                #pragma unroll
                for (int kc = 0; kc < 2; kc++)
                    pf[c][kc] = *(const short8*)&P2[wid][(c*16 + l16)*64 + ((kc*32 + q4*8) ^ swz)];
            // ---- PV swapped: accO^T += mfma(V^T, P^T); vf rows = d, pf cols = q
            __builtin_amdgcn_s_setprio(1);
            #pragma unroll
            for (int ndi = 0; ndi < 4; ndi++) {
                const int rbase = (ndi*16 + l16) * 64;
                short8 vf0 = *(const short8*)&Vs[cb][rbase + ((     q4*8) ^ swz)];
                short8 vf1 = *(const short8*)&Vs[cb][rbase + ((32 + q4*8) ^ swz)];
                accO[0][ndi] = __builtin_amdgcn_mfma_f32_16x16x32_bf16(vf0, pf[0][0], accO[0][ndi], 0, 0, 0);
                accO[0][ndi] = __builtin_amdgcn_mfma_f32_16x16x32_bf16(vf1, pf[0][1], accO[0][ndi], 0, 0, 0);
                accO[1][ndi] = __builtin_amdgcn_mfma_f32_16x16x32_bf16(vf0, pf[1][0], accO[1][ndi], 0, 0, 0);
                accO[1][ndi] = __builtin_amdgcn_mfma_f32_16x16x32_bf16(vf1, pf[1][1], accO[1][ndi], 0, 0, 0);
            }
            __builtin_amdgcn_s_setprio(0);
        }
        if (hasN) {
            *(uint4*)&Ks[nb][ sr     *64 + scs] = nk0;
            *(uint4*)&Ks[nb][(sr+32)*64 + scs]  = nk1;
            *(uint4*)&Vs[nb][ sr     *64 + scs] = nv0;
            *(uint4*)&Vs[nb][(sr+32)*64 + scs]  = nv1;
        }
        __syncthreads();
    }

    // epilogue: reduce l across the 4 q4-groups, normalize, write O (row=q, d from q4*4+r)
    #pragma unroll
    for (int c = 0; c < 2; c++) {
        float l = lacc[c];
        l += __shfl_xor(l, 16);
        l += __shfl_xor(l, 32);
        const float inv = 1.0f / l;
        const size_t row = (size_t)(b*SS + qw + c*16 + l16);
        #pragma unroll
        for (int ndi = 0; ndi < 4; ndi++) {
            ushort4 o;
            o.x = f2bf(accO[c][ndi][0] * inv);
            o.y = f2bf(accO[c][ndi][1] * inv);
            o.z = f2bf(accO[c][ndi][2] * inv);
            o.w = f2bf(accO[c][ndi][3] * inv);
            *(ushort4*)&ctx[row*DM + h*64 + ndi*16 + q4*4] = o;
        }
    }
}

// ---- output projection: 128x64 tiles, BK=32 ----
__launch_bounds__(256)
__global__ void k_gemm_proj(const unsigned short* __restrict__ ctx,
                            const unsigned short* __restrict__ woT,
                            const float* __restrict__ bo,
                            float* __restrict__ out) {
    __shared__ __align__(16) unsigned short As[128][32];
    __shared__ __align__(16) unsigned short Bs[64][32];
    const int t = threadIdx.x;
    const int m0 = blockIdx.x * 128;
    const int n0 = blockIdx.y * 64;
    const int wid = t >> 6, lane = t & 63, q4 = lane >> 4, l16 = lane & 15;
    const int wm = (wid >> 1) * 64, wn = (wid & 1) * 32;

    const int srowA = wid * 32 + (lane >> 2);
    const int srowB = wid * 16 + (lane >> 2);
    const int koff = (lane & 3) * 8;
    const unsigned short* AgL = ctx + (size_t)(m0 + srowA) * DM + koff;
    const unsigned short* AgH = AgL + (size_t)16 * DM;
    const unsigned short* BgL = woT + (size_t)(n0 + srowB) * DM + koff;
    unsigned short* ldsA1 = &As[wid*32][0];
    unsigned short* ldsA2 = &As[wid*32 + 16][0];
    unsigned short* ldsB1 = &Bs[wid*16][0];

    f32x4 acc[4][2];
    for (int i = 0; i < 4; i++) for (int j = 0; j < 2; j++)
        acc[i][j] = (f32x4){0.f, 0.f, 0.f, 0.f};

    for (int kt = 0; kt < DM; kt += 32) {
        gload_lds16(AgL + kt, ldsA1);
        gload_lds16(AgH + kt, ldsA2);
        gload_lds16(BgL + kt, ldsB1);
        __syncthreads();
        short8 af[4], bf[2];
        for (int i = 0; i < 4; i++) af[i] = *(const short8*)&As[wm + i*16 + l16][q4*8];
        for (int i = 0; i < 2; i++) bf[i] = *(const short8*)&Bs[wn + i*16 + l16][q4*8];
        for (int mi = 0; mi < 4; mi++)
            for (int ni = 0; ni < 2; ni++)
                acc[mi][ni] = __builtin_amdgcn_mfma_f32_16x16x32_bf16(af[mi], bf[ni], acc[mi][ni], 0, 0, 0);
        __syncthreads();
    }

    for (int ni = 0; ni < 2; ni++) {
        const int col = n0 + wn + ni*16 + l16;
        const float bsv = bo[col];
        for (int mi = 0; mi < 4; mi++) {
            for (int r = 0; r < 4; r++) {
                const int row = m0 + wm + mi*16 + q4*4 + r;
                out[(size_t)row * DM + col] = acc[mi][ni][r] + bsv;
            }
        }
    }
}

extern "C" void kernel_launch(void* const* d_in, const int* in_sizes, int n_in,
                              void* d_out, int out_size, void* d_ws, size_t ws_size,
                              hipStream_t stream) {
    const float* x  = (const float*)d_in[0];
    const float* wq = (const float*)d_in[2];
    const float* bq = (const float*)d_in[3];
    const float* wk = (const float*)d_in[4];
    const float* bk = (const float*)d_in[5];
    const float* wv = (const float*)d_in[6];
    const float* bv = (const float*)d_in[7];
    const float* wo = (const float*)d_in[8];
    const float* bo = (const float*)d_in[9];
    float* out = (float*)d_out;

    unsigned short* xb  = (unsigned short*)d_ws;           // 4096*768
    unsigned short* wT  = xb + (size_t)MT * DM;            // 4*768*768
    unsigned short* Qb  = wT + (size_t)4 * DM * DM;        // 24*2048*64
    unsigned short* Kb  = Qb + (size_t)BB * NH * SS * DKH;
    unsigned short* Vt  = Kb + (size_t)BB * NH * SS * DKH; // [bh][dk][s]
    unsigned short* ctx = Vt + (size_t)BB * NH * SS * DKH; // 4096*768

    k_conv<<<3072 + 2304, 256, 0, stream>>>(x, xb, wq, wk, wv, wo, wT);
    dim3 g1(MT / 128, NQKV / 128);
    k_gemm_qkv<<<g1, 256, 0, stream>>>(xb, wT, bq, bk, bv, Qb, Kb, Vt);
    k_attn<<<dim3(384), 256, 0, stream>>>(Qb, Kb, Vt, ctx);
    dim3 g3(MT / 128, DM / 64);
    k_gemm_proj<<<g3, 256, 0, stream>>>(ctx, wT + (size_t)3 * DM * DM, bo, out);
}

// Round 3
// 168.682 us; speedup vs baseline: 1.0965x; 1.0965x over previous
//
#include <hip/hip_runtime.h>
#include <hip/hip_bf16.h>
#include <stdint.h>

#define DM   768
#define NH   12
#define DKH  64
#define BB   2
#define SS   2048
#define MT   (BB*SS)          // 4096 rows total
#define NQKV (3*DM)           // 2304

typedef __attribute__((ext_vector_type(8))) short short8;
typedef __attribute__((ext_vector_type(4))) float f32x4;

__device__ __forceinline__ unsigned short f2bf(float f) {
    union { float f; unsigned u; } v; v.f = f;
    unsigned r = v.u + 0x7fffu + ((v.u >> 16) & 1u);
    return (unsigned short)(r >> 16);
}

// async global->LDS, 16B per lane; dst = wave-uniform base + lane*16
__device__ __forceinline__ void gload_lds16(const unsigned short* g, unsigned short* l) {
    __builtin_amdgcn_global_load_lds((const __attribute__((address_space(1))) void*)g,
                                     (__attribute__((address_space(3))) void*)l, 16, 0, 0);
}

// ---- fused input/weight conversion (one launch) ----
__launch_bounds__(256)
__global__ void k_conv(const float* __restrict__ x, unsigned short* __restrict__ xb,
                       const float* __restrict__ wq, const float* __restrict__ wk,
                       const float* __restrict__ wv, const float* __restrict__ wo,
                       unsigned short* __restrict__ wT) {
    __shared__ float tile[32][33];
    const int t = threadIdx.x;
    if (blockIdx.x < 3072) {
        int i = blockIdx.x * 256 + t;
        const float4 v = ((const float4*)x)[i];
        ushort4 o;
        o.x = f2bf(v.x); o.y = f2bf(v.y); o.z = f2bf(v.z); o.w = f2bf(v.w);
        ((ushort4*)xb)[i] = o;
    } else {
        const int cid = blockIdx.x - 3072;            // 0..2303
        const int sel = cid / 576;
        const int rem = cid - sel * 576;
        const int kb = rem / 24, nb = rem - (rem / 24) * 24;
        const float* w = (sel == 0) ? wq : (sel == 1) ? wk : (sel == 2) ? wv : wo;
        const int k0 = kb * 32, n0 = nb * 32;
        const int tx = t & 31, ty = t >> 5;           // (32, 8)
        #pragma unroll
        for (int j = 0; j < 4; j++)
            tile[ty + 8*j][tx] = w[(size_t)(k0 + ty + 8*j) * DM + n0 + tx];
        __syncthreads();
        #pragma unroll
        for (int j = 0; j < 4; j++)
            wT[(size_t)(sel*DM + n0 + ty + 8*j) * DM + k0 + tx] = f2bf(tile[tx][ty + 8*j]);
    }
}

// ---- fused QKV projection, BK=32: Q,K [bh][s][dk] (Q pre-scaled 0.125), V^T [bh][dk][s]
__launch_bounds__(256)
__global__ void k_gemm_qkv(const unsigned short* __restrict__ xb,
                           const unsigned short* __restrict__ wT,
                           const float* __restrict__ bq, const float* __restrict__ bk,
                           const float* __restrict__ bv,
                           unsigned short* __restrict__ Qb,
                           unsigned short* __restrict__ Kb,
                           unsigned short* __restrict__ Vt) {
    __shared__ __align__(16) unsigned short As[128][32];
    __shared__ __align__(16) unsigned short Bs[128][32];
    const int t = threadIdx.x;
    const int m0 = blockIdx.x * 128;
    const int n0 = blockIdx.y * 128;
    const int wid = t >> 6, lane = t & 63, q4 = lane >> 4, l16 = lane & 15;
    const int wm = (wid >> 1) * 64, wn = (wid & 1) * 64;

    const int srow = wid * 32 + (lane >> 2);
    const int koff = (lane & 3) * 8;
    const unsigned short* AgL = xb + (size_t)(m0 + srow) * DM + koff;
    const unsigned short* AgH = AgL + (size_t)16 * DM;
    const unsigned short* BgL = wT + (size_t)(n0 + srow) * DM + koff;
    const unsigned short* BgH = BgL + (size_t)16 * DM;
    unsigned short* ldsA1 = &As[wid*32][0];
    unsigned short* ldsA2 = &As[wid*32 + 16][0];
    unsigned short* ldsB1 = &Bs[wid*32][0];
    unsigned short* ldsB2 = &Bs[wid*32 + 16][0];

    f32x4 acc[4][4];
    for (int i = 0; i < 4; i++) for (int j = 0; j < 4; j++)
        acc[i][j] = (f32x4){0.f, 0.f, 0.f, 0.f};

    for (int kt = 0; kt < DM; kt += 32) {
        gload_lds16(AgL + kt, ldsA1);
        gload_lds16(AgH + kt, ldsA2);
        gload_lds16(BgL + kt, ldsB1);
        gload_lds16(BgH + kt, ldsB2);
        __syncthreads();
        short8 af[4], bf[4];
        for (int i = 0; i < 4; i++) af[i] = *(const short8*)&As[wm + i*16 + l16][q4*8];
        for (int i = 0; i < 4; i++) bf[i] = *(const short8*)&Bs[wn + i*16 + l16][q4*8];
        for (int mi = 0; mi < 4; mi++)
            for (int ni = 0; ni < 4; ni++)
                acc[mi][ni] = __builtin_amdgcn_mfma_f32_16x16x32_bf16(af[mi], bf[ni], acc[mi][ni], 0, 0, 0);
        __syncthreads();
    }

    const int sel = n0 / DM;
    const float* bias = (sel == 0) ? bq : (sel == 1) ? bk : bv;
    for (int ni = 0; ni < 4; ni++) {
        const int col = n0 + wn + ni*16 + l16;
        const int c = col - sel * DM;
        const float bsv = bias[c];
        const int h = c >> 6, d = c & 63;
        for (int mi = 0; mi < 4; mi++) {
            for (int r = 0; r < 4; r++) {
                const int row = m0 + wm + mi*16 + q4*4 + r;
                const int b = row >> 11, s = row & 2047;
                const int bh = b * NH + h;
                float v = acc[mi][ni][r] + bsv;
                if (sel == 0) {
                    Qb[(bh*SS + s)*DKH + d] = f2bf(v * 0.125f);   // fold 1/sqrt(dk), exact
                } else if (sel == 1) {
                    Kb[(bh*SS + s)*DKH + d] = f2bf(v);
                } else {
                    Vt[(bh*DKH + d)*SS + s] = f2bf(v);            // V pre-transposed
                }
            }
        }
    }
}

// ---- causal flash attention v4: swapped-QK engine + KV-split, combine in a
// separate kernel (kernel-boundary coherence => no fences/atomics/races).
// 1152 blocks, 4 waves x 16 q-rows (64 q/block). q-blocks >=16 split KV range
// into 2 even chunks (max 16 serial tiles -> critical path halved). Max-free
// softmax => partials (O_unnorm, l) combine by pure addition in k_combine.
// LDS = 40960 B -> 4 blocks/CU. Unit-major order: XCD x sees bh = x (mod 8).
__device__ const int UNITS[48] = {   // (qblk<<16)|(t0<<8)|t1, heavy-first
  (15<<16)|(0<<8)|16, (31<<16)|(0<<8)|16, (31<<16)|(16<<8)|32, (30<<16)|(0<<8)|16,
  (14<<16)|(0<<8)|15, (29<<16)|(0<<8)|15, (29<<16)|(15<<8)|30, (28<<16)|(0<<8)|15, (30<<16)|(16<<8)|31,
  (13<<16)|(0<<8)|14, (27<<16)|(0<<8)|14, (27<<16)|(14<<8)|28, (26<<16)|(0<<8)|14, (28<<16)|(15<<8)|29,
  (12<<16)|(0<<8)|13, (25<<16)|(0<<8)|13, (25<<16)|(13<<8)|26, (24<<16)|(0<<8)|13, (26<<16)|(14<<8)|27,
  (11<<16)|(0<<8)|12, (23<<16)|(0<<8)|12, (23<<16)|(12<<8)|24, (22<<16)|(0<<8)|12, (24<<16)|(13<<8)|25,
  (10<<16)|(0<<8)|11, (21<<16)|(0<<8)|11, (21<<16)|(11<<8)|22, (20<<16)|(0<<8)|11, (22<<16)|(12<<8)|23,
  ( 9<<16)|(0<<8)|10, (19<<16)|(0<<8)|10, (19<<16)|(10<<8)|20, (18<<16)|(0<<8)|10, (20<<16)|(11<<8)|21,
  ( 8<<16)|(0<<8)| 9, (17<<16)|(0<<8)| 9, (17<<16)|( 9<<8)|18, (16<<16)|(0<<8)| 9, (18<<16)|(10<<8)|19,
  ( 7<<16)|(0<<8)| 8, (16<<16)|( 9<<8)|17,
  ( 6<<16)|(0<<8)| 7, ( 5<<16)|(0<<8)| 6, ( 4<<16)|(0<<8)| 5, ( 3<<16)|(0<<8)| 4,
  ( 2<<16)|(0<<8)| 3, ( 1<<16)|(0<<8)| 2, ( 0<<16)|(0<<8)| 1,
};

__launch_bounds__(256, 4)
__global__ void k_attn(const unsigned short* __restrict__ Qb,
                       const unsigned short* __restrict__ Kb,
                       const unsigned short* __restrict__ Vt,
                       unsigned short* __restrict__ ctx,
                       float* __restrict__ Opart, float* __restrict__ lpart) {
    __shared__ __align__(16) unsigned short Ks[2][64*64];   // [row][col^swz(row)]
    __shared__ __align__(16) unsigned short Vs[2][64*64];
    __shared__ __align__(16) unsigned short P2[4][16*64];   // per-wave P[q][key], swizzled
    const int t = threadIdx.x;
    const int wid = t >> 6, lane = t & 63, q4 = lane >> 4, l16 = lane & 15;

    const int lin = blockIdx.x;           // 0..1151
    const int bh = lin % 24;
    const int info = UNITS[lin / 24];
    const int qblk = info >> 16, t0 = (info >> 8) & 0xff, t1 = info & 0xff;
    const int b = bh / NH, h = bh - b * NH;
    const int qw = qblk * 64 + wid * 16;  // this wave's 16 q-rows

    const unsigned short* Qp = Qb + (size_t)bh * SS * DKH;
    const unsigned short* Kp = Kb + (size_t)bh * SS * DKH;
    const unsigned short* Vp = Vt + (size_t)bh * DKH * SS;

    // staging: 256 threads, 2 rows each for K and V (64 rows x 128B)
    const int sr  = t >> 3;                       // 0..31
    const int sc8 = (t & 7) * 8;                  // short col 0..56
    const int scs = sc8 ^ ((sr & 7) * 8);         // swizzled short col
    const int swz = (l16 & 7) * 8;                // fragment-read swizzle

    short8 qf[2];
    qf[0] = *(const short8*)(Qp + (size_t)(qw + l16)*DKH +      q4*8);
    qf[1] = *(const short8*)(Qp + (size_t)(qw + l16)*DKH + 32 + q4*8);

    f32x4 accO[4];
    #pragma unroll
    for (int j = 0; j < 4; j++) accO[j] = (f32x4){0.f, 0.f, 0.f, 0.f};
    float lacc = 0.f;

    {   // prologue: stage tile t0
        const int kb0 = t0 * 64;
        *(uint4*)&Ks[0][ sr    *64 + scs] = *(const uint4*)(Kp + (size_t)(kb0 + sr)     *DKH + sc8);
        *(uint4*)&Ks[0][(sr+32)*64 + scs] = *(const uint4*)(Kp + (size_t)(kb0 + sr + 32)*DKH + sc8);
        *(uint4*)&Vs[0][ sr    *64 + scs] = *(const uint4*)(Vp + (size_t) sr     *SS + kb0 + sc8);
        *(uint4*)&Vs[0][(sr+32)*64 + scs] = *(const uint4*)(Vp + (size_t)(sr+32) *SS + kb0 + sc8);
    }
    __syncthreads();

    for (int kt = t0; kt < t1; kt++) {
        const int cb = (kt - t0) & 1, nb = cb ^ 1;
        const bool hasN = (kt + 1 < t1);
        uint4 nk0, nk1, nv0, nv1;
        if (hasN) {
            const int kn = (kt + 1) * 64;
            nk0 = *(const uint4*)(Kp + (size_t)(kn + sr)      * DKH + sc8);
            nk1 = *(const uint4*)(Kp + (size_t)(kn + sr + 32) * DKH + sc8);
            nv0 = *(const uint4*)(Vp + (size_t)(sr)      * SS + kn + sc8);
            nv1 = *(const uint4*)(Vp + (size_t)(sr + 32) * SS + kn + sc8);
        }
        // ---- QK^T swapped: St[ni] = S^T, col = q (l16), row = key (q4*4+r)
        f32x4 St[4];
        #pragma unroll
        for (int ni = 0; ni < 4; ni++) St[ni] = (f32x4){0.f, 0.f, 0.f, 0.f};
        __builtin_amdgcn_s_setprio(1);
        #pragma unroll
        for (int ni = 0; ni < 4; ni++) {
            const int rbase = (ni*16 + l16) * 64;
            short8 kf0 = *(const short8*)&Ks[cb][rbase + ((     q4*8) ^ swz)];
            short8 kf1 = *(const short8*)&Ks[cb][rbase + ((32 + q4*8) ^ swz)];
            St[ni] = __builtin_amdgcn_mfma_f32_16x16x32_bf16(kf0, qf[0], St[ni], 0, 0, 0);
            St[ni] = __builtin_amdgcn_mfma_f32_16x16x32_bf16(kf1, qf[1], St[ni], 0, 0, 0);
        }
        __builtin_amdgcn_s_setprio(0);
        // ---- softmax (max-free exp) + transposed P store: 8B packed
        if (kt < qblk) {            // fully unmasked tile
            #pragma unroll
            for (int ni = 0; ni < 4; ni++) {
                float p0 = __expf(St[ni][0]), p1 = __expf(St[ni][1]);
                float p2 = __expf(St[ni][2]), p3 = __expf(St[ni][3]);
                lacc += (p0 + p1) + (p2 + p3);
                union { __hip_bfloat162 v; unsigned u; } u01, u23;
                u01.v = __float22bfloat162_rn(make_float2(p0, p1));
                u23.v = __float22bfloat162_rn(make_float2(p2, p3));
                uint2 pk; pk.x = u01.u; pk.y = u23.u;
                *(uint2*)&P2[wid][l16*64 + ((ni*16 + q4*4) ^ swz)] = pk;
            }
        } else {                    // the single partially-masked (diagonal) tile
            const int qrow = qw + l16;
            #pragma unroll
            for (int ni = 0; ni < 4; ni++) {
                const int key0 = kt*64 + ni*16 + q4*4;
                float p[4];
                #pragma unroll
                for (int r = 0; r < 4; r++) {
                    p[r] = (key0 + r > qrow) ? 0.f : __expf(St[ni][r]);
                    lacc += p[r];
                }
                union { __hip_bfloat162 v; unsigned u; } u01, u23;
                u01.v = __float22bfloat162_rn(make_float2(p[0], p[1]));
                u23.v = __float22bfloat162_rn(make_float2(p[2], p[3]));
                uint2 pk; pk.x = u01.u; pk.y = u23.u;
                *(uint2*)&P2[wid][l16*64 + ((ni*16 + q4*4) ^ swz)] = pk;
            }
        }
        asm volatile("s_waitcnt lgkmcnt(0)" ::: "memory");   // wave-private P round-trip
        short8 pf[2];
        pf[0] = *(const short8*)&P2[wid][l16*64 + ((     q4*8) ^ swz)];
        pf[1] = *(const short8*)&P2[wid][l16*64 + ((32 + q4*8) ^ swz)];
        // ---- PV swapped: accO^T += mfma(V^T, P^T); vf rows = d, pf cols = q
        __builtin_amdgcn_s_setprio(1);
        #pragma unroll
        for (int ndi = 0; ndi < 4; ndi++) {
            const int rbase = (ndi*16 + l16) * 64;
            short8 vf0 = *(const short8*)&Vs[cb][rbase + ((     q4*8) ^ swz)];
            short8 vf1 = *(const short8*)&Vs[cb][rbase + ((32 + q4*8) ^ swz)];
            accO[ndi] = __builtin_amdgcn_mfma_f32_16x16x32_bf16(vf0, pf[0], accO[ndi], 0, 0, 0);
            accO[ndi] = __builtin_amdgcn_mfma_f32_16x16x32_bf16(vf1, pf[1], accO[ndi], 0, 0, 0);
        }
        __builtin_amdgcn_s_setprio(0);
        if (hasN) {
            *(uint4*)&Ks[nb][ sr    *64 + scs] = nk0;
            *(uint4*)&Ks[nb][(sr+32)*64 + scs] = nk1;
            *(uint4*)&Vs[nb][ sr    *64 + scs] = nv0;
            *(uint4*)&Vs[nb][(sr+32)*64 + scs] = nv1;
        }
        __syncthreads();
    }

    // sum l over the 4 q4-groups (each lane ends with the full row sum)
    float l = lacc;
    l += __shfl_xor(l, 16);
    l += __shfl_xor(l, 32);

    if (qblk < 16) {
        // single chunk: normalize + write ctx directly (O^T: d = ndi*16+q4*4+r, q = l16)
        const float inv = 1.0f / l;
        const size_t row = (size_t)(b*SS + qw + l16);
        #pragma unroll
        for (int ndi = 0; ndi < 4; ndi++) {
            ushort4 o;
            o.x = f2bf(accO[ndi][0] * inv);
            o.y = f2bf(accO[ndi][1] * inv);
            o.z = f2bf(accO[ndi][2] * inv);
            o.w = f2bf(accO[ndi][3] * inv);
            *(ushort4*)&ctx[row*DM + h*64 + ndi*16 + q4*4] = o;
        }
    } else {
        // split: write unnormalized partial (f32) + partial l; k_combine finishes.
        const int pair  = bh * 16 + (qblk - 16);       // 0..383
        const int chunk = (t0 != 0);
        const int qloc  = wid * 16 + l16;              // 0..63
        float* Op = Opart + ((size_t)pair * 2 + chunk) * 4096;
        #pragma unroll
        for (int ndi = 0; ndi < 4; ndi++)
            *(f32x4*)&Op[qloc*64 + ndi*16 + q4*4] = accO[ndi];
        if (q4 == 0) lpart[pair*128 + chunk*64 + qloc] = l;
    }
}

// ---- combine the two KV-split partials per 64-row q-block (race-free) ----
__launch_bounds__(256)
__global__ void k_combine(const float* __restrict__ Opart,
                          const float* __restrict__ lpart,
                          unsigned short* __restrict__ ctx) {
    const int pair = blockIdx.x;                   // 0..383
    const int bh = pair >> 4, qblk = 16 + (pair & 15);
    const int b = bh / NH, h = bh - b * NH;
    const int t = threadIdx.x;
    const int q = t >> 2, dg = (t & 3) * 16;
    const float* P0 = Opart + (size_t)pair * 2 * 4096;
    const float* P1 = P0 + 4096;
    const float* L0 = lpart + pair * 128;
    const float inv = 1.0f / (L0[q] + L0[64 + q]);
    const size_t row = (size_t)(b*SS + qblk*64 + q);
    #pragma unroll
    for (int i = 0; i < 4; i++) {
        f32x4 a = *(const f32x4*)&P0[q*64 + dg + i*4];
        f32x4 c = *(const f32x4*)&P1[q*64 + dg + i*4];
        ushort4 o;
        o.x = f2bf((a[0] + c[0]) * inv);
        o.y = f2bf((a[1] + c[1]) * inv);
        o.z = f2bf((a[2] + c[2]) * inv);
        o.w = f2bf((a[3] + c[3]) * inv);
        *(ushort4*)&ctx[row*DM + h*64 + dg + i*4] = o;
    }
}

// ---- output projection: 128x64 tiles, BK=32 ----
__launch_bounds__(256)
__global__ void k_gemm_proj(const unsigned short* __restrict__ ctx,
                            const unsigned short* __restrict__ woT,
                            const float* __restrict__ bo,
                            float* __restrict__ out) {
    __shared__ __align__(16) unsigned short As[128][32];
    __shared__ __align__(16) unsigned short Bs[64][32];
    const int t = threadIdx.x;
    const int m0 = blockIdx.x * 128;
    const int n0 = blockIdx.y * 64;
    const int wid = t >> 6, lane = t & 63, q4 = lane >> 4, l16 = lane & 15;
    const int wm = (wid >> 1) * 64, wn = (wid & 1) * 32;

    const int srowA = wid * 32 + (lane >> 2);
    const int srowB = wid * 16 + (lane >> 2);
    const int koff = (lane & 3) * 8;
    const unsigned short* AgL = ctx + (size_t)(m0 + srowA) * DM + koff;
    const unsigned short* AgH = AgL + (size_t)16 * DM;
    const unsigned short* BgL = woT + (size_t)(n0 + srowB) * DM + koff;
    unsigned short* ldsA1 = &As[wid*32][0];
    unsigned short* ldsA2 = &As[wid*32 + 16][0];
    unsigned short* ldsB1 = &Bs[wid*16][0];

    f32x4 acc[4][2];
    for (int i = 0; i < 4; i++) for (int j = 0; j < 2; j++)
        acc[i][j] = (f32x4){0.f, 0.f, 0.f, 0.f};

    for (int kt = 0; kt < DM; kt += 32) {
        gload_lds16(AgL + kt, ldsA1);
        gload_lds16(AgH + kt, ldsA2);
        gload_lds16(BgL + kt, ldsB1);
        __syncthreads();
        short8 af[4], bf[2];
        for (int i = 0; i < 4; i++) af[i] = *(const short8*)&As[wm + i*16 + l16][q4*8];
        for (int i = 0; i < 2; i++) bf[i] = *(const short8*)&Bs[wn + i*16 + l16][q4*8];
        for (int mi = 0; mi < 4; mi++)
            for (int ni = 0; ni < 2; ni++)
                acc[mi][ni] = __builtin_amdgcn_mfma_f32_16x16x32_bf16(af[mi], bf[ni], acc[mi][ni], 0, 0, 0);
        __syncthreads();
    }

    for (int ni = 0; ni < 2; ni++) {
        const int col = n0 + wn + ni*16 + l16;
        const float bsv = bo[col];
        for (int mi = 0; mi < 4; mi++) {
            for (int r = 0; r < 4; r++) {
                const int row = m0 + wm + mi*16 + q4*4 + r;
                out[(size_t)row * DM + col] = acc[mi][ni][r] + bsv;
            }
        }
    }
}

extern "C" void kernel_launch(void* const* d_in, const int* in_sizes, int n_in,
                              void* d_out, int out_size, void* d_ws, size_t ws_size,
                              hipStream_t stream) {
    const float* x  = (const float*)d_in[0];
    const float* wq = (const float*)d_in[2];
    const float* bq = (const float*)d_in[3];
    const float* wk = (const float*)d_in[4];
    const float* bk = (const float*)d_in[5];
    const float* wv = (const float*)d_in[6];
    const float* bv = (const float*)d_in[7];
    const float* wo = (const float*)d_in[8];
    const float* bo = (const float*)d_in[9];
    float* out = (float*)d_out;

    unsigned short* xb  = (unsigned short*)d_ws;           // 4096*768
    unsigned short* wT  = xb + (size_t)MT * DM;            // 4*768*768
    unsigned short* Qb  = wT + (size_t)4 * DM * DM;        // 24*2048*64
    unsigned short* Kb  = Qb + (size_t)BB * NH * SS * DKH;
    unsigned short* Vt  = Kb + (size_t)BB * NH * SS * DKH; // [bh][dk][s]
    unsigned short* ctx = Vt + (size_t)BB * NH * SS * DKH; // 4096*768
    float* Opart = (float*)(ctx + (size_t)MT * DM);        // 384 pairs x 2 x 64x64 f32
    float* lpart = Opart + (size_t)768 * 4096;             // 384 x 128 f32

    k_conv<<<3072 + 2304, 256, 0, stream>>>(x, xb, wq, wk, wv, wo, wT);
    dim3 g1(MT / 128, NQKV / 128);
    k_gemm_qkv<<<g1, 256, 0, stream>>>(xb, wT, bq, bk, bv, Qb, Kb, Vt);
    k_attn<<<dim3(1152), 256, 0, stream>>>(Qb, Kb, Vt, ctx, Opart, lpart);
    k_combine<<<dim3(384), 256, 0, stream>>>(Opart, lpart, ctx);
    dim3 g3(MT / 128, DM / 64);
    k_gemm_proj<<<g3, 256, 0, stream>>>(ctx, wT + (size_t)3 * DM * DM, bo, out);
}